// Round 3
// baseline (262.889 us; speedup 1.0000x reference)
//
#include <hip/hip_runtime.h>
#include <stdint.h>

#define HW    50176   // 224*224
#define BATCH 16
#define NSEG  196
#define EMB   16
#define MC    16
#define JITTER 0.001f
#define EBLK  14      // emb blocks per batch
#define PXB   3584    // pixels per emb block (50176/14)

// ---------------- packed f32 (VOP3P) helpers -------------------------------
// chol is ISSUE-bound (1 wave/SIMD, ~500 VALU instr x 2cy per interval).
// v_pk_fma_f32 packs two INDEPENDENT fmas into one instruction -> bit-
// identical values, ~22% fewer issued instructions. Serial chains (dot15,
// pivot recursion, tree-norm add order) stay scalar for bit-identity.
typedef float f32x2 __attribute__((ext_vector_type(2)));
typedef float f32x4 __attribute__((ext_vector_type(4)));

__device__ inline f32x2 pk_mul(f32x2 a, f32x2 b) {
  f32x2 d;
  asm("v_pk_mul_f32 %0, %1, %2" : "=v"(d) : "v"(a), "v"(b));
  return d;
}
__device__ inline f32x2 pk_fma(f32x2 a, f32x2 b, f32x2 c) {
  f32x2 d;
  asm("v_pk_fma_f32 %0, %1, %2, %3" : "=v"(d) : "v"(a), "v"(b), "v"(c));
  return d;
}

// 15-float row held as 7 packed pairs + tail element
struct Row15 { f32x2 p[7]; float e14; };

// serial j-ascending dot (bit-identity requires this exact order);
// reading .x/.y of a pair is a plain VGPR read (free)
__device__ inline float dot15p(const Row15& a, const Row15& b) {
  float d = 0.0f;
#pragma unroll
  for (int j = 0; j < 7; ++j) {
    d = fmaf(a.p[j].x, b.p[j].x, d);
    d = fmaf(a.p[j].y, b.p[j].y, d);
  }
  return fmaf(a.e14, b.e14, d);
}

// rt -= bd * rf  (elementwise fmaf(-bd, rf, rt), packed; exact sign flip)
__device__ inline void rowaxpy(float bd, const Row15& rf, Row15& rt) {
  float nbd = -bd;
  f32x2 n2; n2.x = nbd; n2.y = nbd;
#pragma unroll
  for (int j = 0; j < 7; ++j) rt.p[j] = pk_fma(n2, rf.p[j], rt.p[j]);
  rt.e14 = fmaf(nbd, rf.e14, rt.e14);
}

// R11 tree-norm + rsq/rcp scalar chain; squares packed (independent muls,
// identical products), adds in the original tree order.
__device__ inline void pivot_scalars_p(const Row15& r, float& invd,
                                       float& dd, float& beta) {
  const float sj = 0.031622776601683794f;  // sqrt(jitter)
  f32x2 s0 = pk_mul(r.p[0], r.p[0]);   // {t0', t1}  (t0' unused)
  f32x2 s1 = pk_mul(r.p[1], r.p[1]);   // {t2, t3}
  f32x2 s2 = pk_mul(r.p[2], r.p[2]);   // {t4, t5}
  f32x2 s3 = pk_mul(r.p[3], r.p[3]);   // {t6, t7}
  f32x2 s4 = pk_mul(r.p[4], r.p[4]);   // {t8, t9}
  f32x2 s5 = pk_mul(r.p[5], r.p[5]);   // {t10, t11}
  f32x2 s6 = pk_mul(r.p[6], r.p[6]);   // {t12, t13}
  float t0 = fmaf(r.p[0].x, r.p[0].x, JITTER);
  float t14 = r.e14 * r.e14;
  float u0 = t0 + s0.y;
  float u1 = s1.x + s1.y;
  float u2 = s2.x + s2.y;
  float u3 = s3.x + s3.y;
  float u4 = s4.x + s4.y;
  float u5 = s5.x + s5.y;
  float u6 = s6.x + s6.y;
  float v0 = u0 + u1, v1 = u2 + u3, v2 = u4 + u5, v3 = u6 + t14;
  float jn = (v0 + v1) + (v2 + v3);
  invd = __builtin_amdgcn_rsqf(jn);
  dd = jn * invd;
  beta = (invd * invd) * __builtin_amdgcn_rcpf(fmaf(sj, invd, 1.0f));
}

// load a published 16-float row (15 used) from LDS via 4x b128
__device__ inline void load_row(const float* p, Row15& r) {
  f32x4 a0 = *(const f32x4*)(p + 0);
  f32x4 a1 = *(const f32x4*)(p + 4);
  f32x4 a2 = *(const f32x4*)(p + 8);
  f32x4 a3 = *(const f32x4*)(p + 12);
  r.p[0].x = a0.x; r.p[0].y = a0.y;
  r.p[1].x = a0.z; r.p[1].y = a0.w;
  r.p[2].x = a1.x; r.p[2].y = a1.y;
  r.p[3].x = a1.z; r.p[3].y = a1.w;
  r.p[4].x = a2.x; r.p[4].y = a2.y;
  r.p[5].x = a2.z; r.p[5].y = a2.w;
  r.p[6].x = a3.x; r.p[6].y = a3.y;
  r.e14    = a3.z;
}

// ---------------- threefry2x32 (20 rounds), bit-exact vs JAX ----------------
__host__ __device__ inline void threefry2x32(uint32_t k0, uint32_t k1,
                                             uint32_t x0, uint32_t x1,
                                             uint32_t& o0, uint32_t& o1) {
  uint32_t k2 = k0 ^ k1 ^ 0x1BD11BDAu;
#define TFR(r) { x0 += x1; x1 = (x1 << (r)) | (x1 >> (32 - (r))); x1 ^= x0; }
  x0 += k0; x1 += k1;
  TFR(13) TFR(15) TFR(26) TFR(6)
  x0 += k1; x1 += k2 + 1u;
  TFR(17) TFR(29) TFR(16) TFR(24)
  x0 += k2; x1 += k0 + 2u;
  TFR(13) TFR(15) TFR(26) TFR(6)
  x0 += k0; x1 += k1 + 3u;
  TFR(17) TFR(29) TFR(16) TFR(24)
  x0 += k1; x1 += k2 + 4u;
  TFR(13) TFR(15) TFR(26) TFR(6)
  x0 += k2; x1 += k0 + 5u;
#undef TFR
  o0 = x0; o1 = x1;
}

// XLA ErfInv (f32), Giles polynomial
__device__ inline float erfinv_f32(float x) {
  float w = -log1pf(-x * x);
  float p;
  if (w < 5.0f) {
    w = w - 2.5f;
    p = 2.81022636e-08f;
    p = 3.43273939e-07f + p * w;
    p = -3.5233877e-06f + p * w;
    p = -4.39150654e-06f + p * w;
    p = 0.00021858087f + p * w;
    p = -0.00125372503f + p * w;
    p = -0.00417768164f + p * w;
    p = 0.246640727f + p * w;
    p = 1.50140941f + p * w;
  } else {
    w = sqrtf(w) - 3.0f;
    p = -0.000200214257f;
    p = 0.000100950558f + p * w;
    p = 0.00134934322f + p * w;
    p = -0.00367342844f + p * w;
    p = 0.00573950773f + p * w;
    p = -0.0076224613f + p * w;
    p = 0.00943887047f + p * w;
    p = 1.00167406f + p * w;
    p = 2.83297682f + p * w;
  }
  return p * x;
}

__device__ inline float bits_to_f01(uint32_t bits) {
  uint32_t fb = (bits >> 9) | 0x3F800000u;
  return __uint_as_float(fb) - 1.0f;
}

// ---------------- K1: pixel_probs + per-block segment sums of x,cnt --------
__global__ __launch_bounds__(256) void emb_kernel(
    const float* __restrict__ x, const int* __restrict__ groups,
    const float* __restrict__ Wc, const float* __restrict__ bc,
    float* __restrict__ partial, float* __restrict__ pixel_probs) {
  __shared__ float lsum[4 * NSEG];  // [c][g]
  int b = blockIdx.x / EBLK;
  int blk = blockIdx.x % EBLK;
  int tid = threadIdx.x;
  for (int i = tid; i < 4 * NSEG; i += 256) lsum[i] = 0.0f;
  __syncthreads();
  const float* xb = x + (size_t)b * 3 * HW;
  float w0 = Wc[0], w1 = Wc[1], w2 = Wc[2], b0 = bc[0];
  for (int k = 0; k < PXB / 512; ++k) {  // 7 iters, 512 px per block-iter
    int p = blk * PXB + (k * 256 + tid) * 2;
    float2 x0 = *(const float2*)(xb + p);
    float2 x1 = *(const float2*)(xb + HW + p);
    float2 x2 = *(const float2*)(xb + 2 * HW + p);
    int2 gg = *(const int2*)(groups + b * HW + p);
    float ea = w0 * x0.x + w1 * x1.x;
    ea = ea + w2 * x2.x + b0;
    float eb = w0 * x0.y + w1 * x1.y;
    eb = eb + w2 * x2.y + b0;
    f32x2 pp;
    pp.x = 1.0f / (1.0f + expf(-ea));
    pp.y = 1.0f / (1.0f + expf(-eb));
    __builtin_nontemporal_store(pp, (f32x2*)(pixel_probs + b * HW + p));
    atomicAdd(&lsum[gg.x], x0.x);
    atomicAdd(&lsum[NSEG + gg.x], x1.x);
    atomicAdd(&lsum[2 * NSEG + gg.x], x2.x);
    atomicAdd(&lsum[3 * NSEG + gg.x], 1.0f);
    atomicAdd(&lsum[gg.y], x0.y);
    atomicAdd(&lsum[NSEG + gg.y], x1.y);
    atomicAdd(&lsum[2 * NSEG + gg.y], x2.y);
    atomicAdd(&lsum[3 * NSEG + gg.y], 1.0f);
  }
  __syncthreads();
  float* pb = partial + (size_t)blockIdx.x * (4 * NSEG);
  if (tid < NSEG) {
#pragma unroll
    for (int c = 0; c < 4; ++c) pb[c * NSEG + tid] = lsum[c * NSEG + tid];
  }
}

// ---------------- K2: main — sigma tile blocks + chol blocks ---------------
// chol inner loop in packed f32 (Row15) — bit-identical values, ~22% fewer
// issued VALU instructions. Structure/barrier schedule unchanged.
__global__ __launch_bounds__(256, 1) void main_kernel(
    const float* __restrict__ partial, const float* __restrict__ Wc,
    const float* __restrict__ bc,
    uint32_t kg0, uint32_t kg1, uint32_t ku0, uint32_t ku1,
    float* __restrict__ group_probs, float* __restrict__ sigma_out,
    float* __restrict__ hard) {
  int bid = blockIdx.x;
  int tid = threadIdx.x;

  if (bid < 112) {
    // ================= sigma tile block (unchanged op order) ==============
    int b = bid / 7;
    int tile = bid % 7;
    __shared__ float ge_s[15][NSEG];
    if (tid < NSEG) {
      float sx0 = 0.0f, sx1 = 0.0f, sx2 = 0.0f, cn = 0.0f;
      for (int bb = 0; bb < EBLK; ++bb) {
        const float* pb = partial + (size_t)(b * EBLK + bb) * (4 * NSEG);
        sx0 += pb[tid]; sx1 += pb[NSEG + tid];
        sx2 += pb[2 * NSEG + tid]; cn += pb[3 * NSEG + tid];
      }
      float denom = fmaxf(cn, 1.0f);
#pragma unroll
      for (int j = 1; j < EMB; ++j) {
        float e = Wc[j * 3 + 0] * sx0 + Wc[j * 3 + 1] * sx1;
        e = e + Wc[j * 3 + 2] * sx2 + bc[j] * cn;
        ge_s[j - 1][tid] = e / denom;
      }
    }
    __syncthreads();
    if (tid < NSEG) {
      int t = tid;
      float gt[15];
#pragma unroll
      for (int j = 0; j < 15; ++j) gt[j] = ge_s[j][t];
      for (int r = 0; r < 28; ++r) {
        int s = tile * 28 + r;
        float a = 0.0f;
#pragma unroll
        for (int j = 0; j < 15; ++j) a = fmaf(ge_s[j][s], gt[j], a);
        if (s == t) a += JITTER;
        sigma_out[((size_t)b * NSEG + s) * NSEG + t] = a;
      }
    }
    return;
  }

  // ================= chol block =================
  int b = bid - 112;
  __shared__ float ge[15][NSEG];                 // 11.76 KB
  __shared__ float mu_l[NSEG];
  __shared__ float eps_lds[NSEG * MC];           // 12.25 KB
  __shared__ __align__(16) float pbuf[2][4][16]; // raw next-panel rows

  // eps = sqrt(2)*erfinv(bits) straight into LDS
  for (int t = tid; t < NSEG * MC; t += 256) {
    uint32_t a0, a1;
    threefry2x32(kg0, kg1, 0u, (uint32_t)(b * NSEG * MC + t), a0, a1);
    float f = bits_to_f01(a0 ^ a1);
    const float lo = -0.99999994f;  // nextafter(-1,0)
    float u = fmaxf(lo, f * (1.0f - lo) + lo);
    eps_lds[t] = 1.4142135623730951f * erfinv_f32(u);
  }

  // stats (identical op order)
  if (tid < NSEG) {
    float sx0 = 0.0f, sx1 = 0.0f, sx2 = 0.0f, cn = 0.0f;
    for (int bb = 0; bb < EBLK; ++bb) {
      const float* pb = partial + (size_t)(b * EBLK + bb) * (4 * NSEG);
      sx0 += pb[tid]; sx1 += pb[NSEG + tid];
      sx2 += pb[2 * NSEG + tid]; cn += pb[3 * NSEG + tid];
    }
    float denom = fmaxf(cn, 1.0f);
#pragma unroll
    for (int j = 0; j < EMB; ++j) {
      float e = Wc[j * 3 + 0] * sx0 + Wc[j * 3 + 1] * sx1;
      e = e + Wc[j * 3 + 2] * sx2 + bc[j] * cn;
      float v = e / denom;
      if (j == 0) {
        mu_l[tid] = v;
        group_probs[b * NSEG + tid] = 1.0f / (1.0f + expf(-v));
      } else {
        ge[j - 1][tid] = v;
      }
    }
  }
  __syncthreads();  // ge, mu_l, eps_lds visible

  int i = tid;  // this thread's row
  Row15 g;
#pragma unroll
  for (int j = 0; j < 7; ++j) {
    g.p[j].x = (i < NSEG) ? ge[2 * j][i] : 0.0f;
    g.p[j].y = (i < NSEG) ? ge[2 * j + 1][i] : 0.0f;
  }
  g.e14 = (i < NSEG) ? ge[14][i] : 0.0f;

  f32x2 acc2[8];
#pragma unroll
  for (int m = 0; m < 8; ++m) { acc2[m].x = 0.0f; acc2[m].y = 0.0f; }

  if (tid < 4) {  // publish raw rows 0..3 for interval 0
    float* pw = &pbuf[0][tid][0];
#pragma unroll
    for (int j = 0; j < 7; ++j) { pw[2 * j] = g.p[j].x; pw[2 * j + 1] = g.p[j].y; }
    pw[14] = g.e14;
  }
  __syncthreads();

// apply one finished pivot (row rv, index K) to own row — exact sequence:
// dot -> w -> acc fma (m ascending, packed pairs) -> g update (packed)
#define APPLY_PIVOT(rv, invd_, dd_, beta_, K)                               \
  {                                                                         \
    float dot = dot15p(g, rv);                                              \
    float w = (i > (K)) ? dot * (invd_)                                     \
                        : ((i == (K)) ? (dd_) : 0.0f);                      \
    f32x2 ww; ww.x = w; ww.y = w;                                           \
    const f32x4* ep4 = (const f32x4*)(eps_lds + (K) * MC);                  \
    f32x4 e0 = ep4[0], e1 = ep4[1], e2 = ep4[2], e3 = ep4[3];               \
    f32x2 ek[8];                                                            \
    ek[0].x = e0.x; ek[0].y = e0.y;  ek[1].x = e0.z; ek[1].y = e0.w;        \
    ek[2].x = e1.x; ek[2].y = e1.y;  ek[3].x = e1.z; ek[3].y = e1.w;        \
    ek[4].x = e2.x; ek[4].y = e2.y;  ek[5].x = e2.z; ek[5].y = e2.w;        \
    ek[6].x = e3.x; ek[6].y = e3.y;  ek[7].x = e3.z; ek[7].y = e3.w;        \
    _Pragma("unroll")                                                       \
    for (int m = 0; m < 8; ++m) acc2[m] = pk_fma(ww, ek[m], acc2[m]);       \
    float bd = (beta_) * dot;                                               \
    rowaxpy(bd, rv, g);                                                     \
  }

  for (int t49 = 0; t49 < 49; ++t49) {
    const float* pb0 = &pbuf[t49 & 1][0][0];
    Row15 r0, r1, r2, r3;
    load_row(pb0 + 0,  r0);
    load_row(pb0 + 16, r1);
    load_row(pb0 + 32, r2);
    load_row(pb0 + 48, r3);

    // derive the 4 finished pivots (exact serial op order)
    float invd0, dd0, beta0, invd1, dd1, beta1;
    float invd2, dd2, beta2, invd3, dd3, beta3;
    pivot_scalars_p(r0, invd0, dd0, beta0);
    {
      float d = dot15p(r1, r0);
      rowaxpy(beta0 * d, r0, r1);
    }
    pivot_scalars_p(r1, invd1, dd1, beta1);
    {
      float d = dot15p(r2, r0);
      rowaxpy(beta0 * d, r0, r2);
      d = dot15p(r2, r1);
      rowaxpy(beta1 * d, r1, r2);
    }
    pivot_scalars_p(r2, invd2, dd2, beta2);
    {
      float d = dot15p(r3, r0);
      rowaxpy(beta0 * d, r0, r3);
      d = dot15p(r3, r1);
      rowaxpy(beta1 * d, r1, r3);
      d = dot15p(r3, r2);
      rowaxpy(beta2 * d, r2, r3);
    }
    pivot_scalars_p(r3, invd3, dd3, beta3);

    // apply 4 pivots to own row, ascending k
    int k0 = 4 * t49;
    APPLY_PIVOT(r0, invd0, dd0, beta0, k0 + 0)
    APPLY_PIVOT(r1, invd1, dd1, beta1, k0 + 1)
    APPLY_PIVOT(r2, invd2, dd2, beta2, k0 + 2)
    APPLY_PIVOT(r3, invd3, dd3, beta3, k0 + 3)

    // publish raw rows for next interval (owners: rows 4(t+1)..4(t+1)+3)
    int nb = 4 * (t49 + 1);
    if (i >= nb && i < nb + 4) {  // t49=48 -> rows 196..199: zeros, never read
      float* pw = &pbuf[(t49 + 1) & 1][i - nb][0];
#pragma unroll
      for (int j = 0; j < 7; ++j) { pw[2 * j] = g.p[j].x; pw[2 * j + 1] = g.p[j].y; }
      pw[14] = g.e14;
    }
    __syncthreads();
  }
#undef APPLY_PIVOT

  // epilogue: hard = (mu + L@eps + logistic) > 0
  if (i < NSEG) {
    float mui = mu_l[i];
    f32x4 outv[4];
    float* op = (float*)outv;
#pragma unroll
    for (int m = 0; m < 16; ++m) {
      uint32_t a0, a1;
      threefry2x32(ku0, ku1, 0u, (uint32_t)(b * NSEG * MC + i * MC + m), a0, a1);
      float f = bits_to_f01(a0 ^ a1);
      const float mn = 1e-6f;
      const float mx = (float)(1.0 - 1e-6);
      float uu = fmaxf(mn, f * (mx - mn) + mn);
      float lg = logf(uu) - log1pf(-uu);
      float am = (m & 1) ? acc2[m >> 1].y : acc2[m >> 1].x;  // acc[m], static idx
      float z = mui + am + lg;
      op[m] = (z > 0.0f) ? 1.0f : 0.0f;
    }
    f32x4* hp = (f32x4*)(hard + ((size_t)b * NSEG + i) * MC);
#pragma unroll
    for (int q = 0; q < 4; ++q) hp[q] = outv[q];
  }
}

// ---------------- K3: mask gather — one thread per (b,p,q), c-loop ---------
// Write-BW-bound (154 MB compulsory). Nontemporal stores keep the streaming
// output from churning L2 dirty lines (hard-gather stays L2-resident).
__global__ __launch_bounds__(256) void mask_kernel(
    const int* __restrict__ groups, const float* __restrict__ hard,
    f32x4* __restrict__ out) {
  int idx = blockIdx.x * 256 + threadIdx.x;   // (b, p, q)
  if (idx >= BATCH * HW * 4) return;          // 3,211,264 threads exactly
  int q = idx & 3;
  int bp = idx >> 2;                          // b*HW + p
  int b = bp / HW;
  int p = bp - b * HW;
  int g = groups[bp];
  f32x4 v = ((const f32x4*)hard)[(b * NSEG + g) * 4 + q];
  size_t base = ((size_t)(b * 3) * HW + p) * 4 + q;  // f32x4 index for c=0
  __builtin_nontemporal_store(v, &out[base]);
  __builtin_nontemporal_store(v, &out[base + (size_t)HW * 4]);       // c=1
  __builtin_nontemporal_store(v, &out[base + (size_t)2 * HW * 4]);   // c=2
}

extern "C" void kernel_launch(void* const* d_in, const int* in_sizes, int n_in,
                              void* d_out, int out_size, void* d_ws, size_t ws_size,
                              hipStream_t stream) {
  const float* x = (const float*)d_in[0];
  const int* groups = (const int*)d_in[1];
  const float* Wc = (const float*)d_in[2];
  const float* bc = (const float*)d_in[3];

  float* out = (float*)d_out;
  float* mask_out = out;                         // 38,535,168
  float* gp_out = out + 38535168;                //      3,136
  float* pp_out = gp_out + 3136;                 //    802,816
  float* sig_out = pp_out + 802816;              //    614,656

  float* ws = (float*)d_ws;
  float* partial = ws;                           // 224*784 = 175,616
  float* hard    = ws + 175616;                  //  50,176 (own region)

  emb_kernel<<<BATCH * EBLK, 256, 0, stream>>>(x, groups, Wc, bc, partial, pp_out);

  uint32_t kg0, kg1, ku0, ku1;
  threefry2x32(0u, 42u, 0u, 0u, kg0, kg1);
  threefry2x32(0u, 42u, 0u, 1u, ku0, ku1);

  main_kernel<<<128, 256, 0, stream>>>(partial, Wc, bc, kg0, kg1, ku0, ku1,
                                       gp_out, sig_out, hard);
  mask_kernel<<<(BATCH * HW * 4 + 255) / 256, 256, 0, stream>>>(
      groups, hard, (f32x4*)mask_out);
}